// Round 1
// baseline (237.676 us; speedup 1.0000x reference)
//
#include <hip/hip_runtime.h>

#define C_IN   128
#define H_IN   56
#define W_IN   56
#define HW     3136      // 56*56
#define CHW    401408    // 128*3136
#define O_OUT  256
#define OHW    802816    // 256*3136

#define BM 256
#define BN 128
#define LDSW 64          // swizzled, unpadded row width (ushorts) [old path]
#define LDK 72           // fallback padded layout
#define XTP 132          // xt transpose LDS row stride (ushorts)

// ---- new-path geometry ----
#define PH 58            // padded spatial dim (56 + 2)
#define PROW 7424        // 58*128 ushorts per padded row
#define PATCH_PIX 348    // 6*58 pixels per block patch

typedef __bf16 bf16x8 __attribute__((ext_vector_type(8)));
typedef float  f32x4  __attribute__((ext_vector_type(4)));
typedef unsigned short ushort_t;
typedef ushort_t ushort8 __attribute__((ext_vector_type(8)));

__device__ __forceinline__ ushort_t f2bf(float f) {
    union { float f; unsigned u; } v; v.f = f;
    unsigned r = (v.u + 0x7fffu + ((v.u >> 16) & 1u)) >> 16;
    return (ushort_t)r;
}

typedef const __attribute__((address_space(1))) unsigned int* gas_ptr;
typedef __attribute__((address_space(3))) unsigned int* las_ptr;
__device__ __forceinline__ void gl_lds16(const void* g, void* l) {
    // async global->LDS, 16B per lane; LDS dest = uniform base + lane*16
    __builtin_amdgcn_global_load_lds((gas_ptr)g, (las_ptr)l, 16, 0, 0);
}

// ============================ NEW FAST PATH ============================

// Weights: w[o][c][kh][kw] fp32 -> wbf[stage s][o][slot][8] bf16,
// s = (kh*3+kw)*2 + (c>>6); slot = ((c>>3)&7) ^ (o&7)  (XOR pre-swizzle so
// conv3's LDS staging is a pure linear copy and frag reads are conflict-free).
__global__ void wt2_kernel(const float* __restrict__ w, ushort_t* __restrict__ wbf) {
    int idx = blockIdx.x * 256 + threadIdx.x;        // 9*256*128 = 294912
    if (idx >= 9 * 256 * 128) return;
    int pos = idx >> 15;
    int rem = idx & 32767;
    int o   = rem >> 7;
    int c   = rem & 127;
    int s    = pos * 2 + (c >> 6);
    int slot = ((c >> 3) & 7) ^ (o & 7);
    wbf[((s * 256 + o) << 6) + (slot << 3) + (c & 7)] = f2bf(w[o * 1152 + c * 9 + pos]);
}

// x fp32 NCHW -> padded swizzled bf16 NHWC: xbp[n][h'][w'][slot][8],
// h',w' in [0,58), border rows/cols zero, slot = gg ^ (w'&7).
// One block per (n, h') row; border rows just zero-fill.
__global__ __launch_bounds__(256)
void xt2_kernel(const float* __restrict__ x, ushort_t* __restrict__ xbp) {
    const int b  = blockIdx.x;            // 0..1855  (32*58)
    const int n  = b / PH;
    const int hp = b - n * PH;
    ushort_t* orow = xbp + (size_t)(n * PH + hp) * PROW;
    const int t = threadIdx.x;
    ushort8 z = ushort8{0,0,0,0,0,0,0,0};

    if (hp == 0 || hp == 57) {
        #pragma unroll
        for (int i = 0; i < 4; ++i) {
            int u = i * 256 + t;
            if (u < 928) *(ushort8*)(orow + u * 8) = z;
        }
        return;
    }

    __shared__ ushort_t T[56 * XTP];      // [w][c], 14784 B
    const int h = hp - 1;
    const float* src = x + (size_t)n * CHW + h * W_IN;
    #pragma unroll
    for (int i = 0; i < 7; ++i) {
        int g  = i * 256 + t;             // 0..1791 = 128 ch * 14 float4
        int c  = g / 14;
        int f4 = g - c * 14;
        f32x4 v = *(const f32x4*)(src + (size_t)c * HW + f4 * 4);
        #pragma unroll
        for (int j = 0; j < 4; ++j)
            T[(f4 * 4 + j) * XTP + c] = f2bf(v[j]);
    }
    __syncthreads();
    #pragma unroll
    for (int i = 0; i < 4; ++i) {
        int u = i * 256 + t;              // 0..927 = 58 w' * 16 groups
        if (u < 928) {
            int wp = u >> 4, gg = u & 15;
            ushort8 v = (wp == 0 || wp == 57) ? z
                        : *(const ushort8*)(&T[(wp - 1) * XTP + gg * 8]);
            *(ushort8*)(orow + wp * 128 + ((gg ^ (wp & 7)) << 3)) = v;
        }
    }
}

// Implicit GEMM with a persistent input patch:
//  - block = 4 output rows x 56 w x 256 o  (n = b/14, h0 = (b%14)*4)
//  - patch: 6 padded rows (89088 B) staged ONCE via global_load_lds (linear copy)
//  - weights: 18 stages of 32 KB, double-buffered, 1-deep prefetch under MFMAs
//  - one vmcnt(0)+barrier per stage (18/block vs 36 before)
//  - per-wave tile 64o x 112pix: 56 MFMA per stage per wave
__global__ __launch_bounds__(512, 2)
void conv3_kernel(const ushort_t* __restrict__ xbp, const ushort_t* __restrict__ wbf,
                  const float* __restrict__ bias, float* __restrict__ out) {
    __shared__ ushort_t patch[PATCH_PIX * 128];   // 89088 B
    __shared__ ushort_t wlds[2][256 * 64];        // 2 x 32768 B  (total LDS 151 KB)

    const int tid  = threadIdx.x;
    const int lane = tid & 63;
    const int wave = tid >> 6;
    const int wm   = wave >> 1;           // 0..3  o-group
    const int wn   = wave & 1;            // 0..1  pixel half
    const int l15  = lane & 15;
    const int quad = lane >> 4;
    const int om   = wm * 64;

    const int b  = blockIdx.x;            // 0..447
    const int n  = b / 14;
    const int hg = b - n * 14;
    const int h0 = hg * 4;

    int ppix[7], wlo[7], obo[7];
    #pragma unroll
    for (int u = 0; u < 7; ++u) {
        int p  = wn * 112 + u * 16 + l15; // 0..223 within block tile
        int pr = p / 56;                  // 0..3 output row in block
        int ww = p - pr * 56;             // 0..55
        ppix[u] = (pr * PH + ww) * 128;   // patch ushort offset (kh=kw=0)
        wlo[u]  = ww;                     // swizzle key base
        obo[u]  = (h0 + pr) * W_IN + ww;  // out spatial offset
    }

    f32x4 acc[4][7];
    #pragma unroll
    for (int t = 0; t < 4; ++t)
        #pragma unroll
        for (int u = 0; u < 7; ++u)
            acc[t][u] = f32x4{0.f, 0.f, 0.f, 0.f};

    // ---- prologue: stage patch (87 KiB-calls) + weight stage 0 ----
    {
        const char* xs = (const char*)(xbp + (size_t)(n * PH + h0) * PROW);
        char* pb = (char*)patch;
        #pragma unroll
        for (int jj = 0; jj < 11; ++jj) {
            int j = jj * 8 + wave;        // 0..86 (87*1024 = 89088 exactly)
            if (j < 87) gl_lds16(xs + j * 1024 + lane * 16, pb + j * 1024);
        }
        const char* wg = (const char*)wbf;          // stage 0
        char* wb = (char*)wlds[0];
        #pragma unroll
        for (int j2 = 0; j2 < 4; ++j2) {
            int j = j2 * 8 + wave;        // 0..31 (32 KB)
            gl_lds16(wg + j * 1024 + lane * 16, wb + j * 1024);
        }
    }
    asm volatile("s_waitcnt vmcnt(0)" ::: "memory");
    __syncthreads();

    int s = 0, cur = 0;
    for (int kh = 0; kh < 3; ++kh) {
        #pragma unroll
        for (int kw = 0; kw < 3; ++kw) {
            const int poff = (kh * PH + kw) * 128;
            #pragma unroll
            for (int half = 0; half < 2; ++half) {
                const ushort_t* wcur = wlds[cur];
                // prefetch next weight stage into the other buffer
                if (s < 17) {
                    const char* wg = (const char*)wbf + (size_t)(s + 1) * 32768;
                    char* wb = (char*)wlds[cur ^ 1];
                    #pragma unroll
                    for (int j2 = 0; j2 < 4; ++j2) {
                        int j = j2 * 8 + wave;
                        gl_lds16(wg + j * 1024 + lane * 16, wb + j * 1024);
                    }
                }
                #pragma unroll
                for (int ks = 0; ks < 2; ++ks) {
                    const int k8  = ks * 4 + quad;     // within-stage c-group
                    const int k16 = half * 8 + k8;     // within-128 c-group
                    bf16x8 af[4], bfv[7];
                    #pragma unroll
                    for (int t = 0; t < 4; ++t) {
                        int o = om + t * 16 + l15;
                        af[t] = *(const bf16x8*)(wcur + (o << 6) + ((k8 ^ (o & 7)) << 3));
                    }
                    #pragma unroll
                    for (int u = 0; u < 7; ++u) {
                        int slot = k16 ^ ((wlo[u] + kw) & 7);
                        bfv[u] = *(const bf16x8*)(patch + ppix[u] + poff + (slot << 3));
                    }
                    #pragma unroll
                    for (int t = 0; t < 4; ++t)
                        #pragma unroll
                        for (int u = 0; u < 7; ++u)
                            acc[t][u] = __builtin_amdgcn_mfma_f32_16x16x32_bf16(
                                            af[t], bfv[u], acc[t][u], 0, 0, 0);
                }
                asm volatile("s_waitcnt vmcnt(0)" ::: "memory");
                __syncthreads();
                cur ^= 1; ++s;
            }
        }
    }

    // ---- epilogue ----
    f32x4 bv[4];
    #pragma unroll
    for (int t = 0; t < 4; ++t)
        bv[t] = *(const f32x4*)(bias + om + t * 16 + quad * 4);
    float* outn = out + (size_t)n * OHW;
    #pragma unroll
    for (int u = 0; u < 7; ++u) {
        float* op = outn + obo[u];
        #pragma unroll
        for (int t = 0; t < 4; ++t) {
            const int o0 = om + t * 16 + quad * 4;
            #pragma unroll
            for (int r = 0; r < 4; ++r)
                op[(size_t)(o0 + r) * HW] = acc[t][u][r] + bv[t][r];
        }
    }
}

// ============================ OLD PATH (fallbacks, verbatim) ============================

__global__ void wt_kernel(const float* __restrict__ w, ushort_t* __restrict__ wbf) {
    int idx = blockIdx.x * 256 + threadIdx.x;        // 9*256*128 = 294912
    if (idx >= 9 * 256 * 128) return;
    int pos = idx >> 15;
    int rem = idx & 32767;
    int o   = rem >> 7;
    int c   = rem & 127;
    wbf[idx] = f2bf(w[o * 1152 + c * 9 + pos]);
}

__global__ __launch_bounds__(256)
void xt_kernel(const float* __restrict__ x, ushort_t* __restrict__ xb) {
    __shared__ ushort_t T[64 * XTP];
    const int t  = threadIdx.x;
    const int tb = blockIdx.x;
    const int n   = tb / 49;
    const int hw0 = (tb - n * 49) * 64;
    const float* src = x + (long)n * CHW + hw0;

    #pragma unroll
    for (int i = 0; i < 8; ++i) {
        const int g  = i * 256 + t;
        const int c  = g >> 4;
        const int p4 = g & 15;
        f32x4 v = *(const f32x4*)(src + (long)c * HW + p4 * 4);
        #pragma unroll
        for (int j = 0; j < 4; ++j)
            T[(p4 * 4 + j) * XTP + c] = f2bf(v[j]);
    }
    __syncthreads();

    ushort_t* dst = xb + ((long)n * HW + hw0) * 128;
    #pragma unroll
    for (int s = 0; s < 4; ++s) {
        const int idx = s * 256 + t;
        const int pix = idx >> 4;
        const int grp = idx & 15;
        ushort8 v = *(const ushort8*)(&T[pix * XTP + grp * 8]);
        *(ushort8*)(dst + pix * 128 + grp * 8) = v;
    }
}

__global__ __launch_bounds__(512, 4)
void conv2_kernel(const ushort_t* __restrict__ xb, const ushort_t* __restrict__ wbf,
                  const float* __restrict__ bias, float* __restrict__ out) {
    __shared__ ushort_t As[BM * LDSW];
    __shared__ ushort_t Bs[BN * LDSW];

    const int tid  = threadIdx.x;
    const int lane = tid & 63;
    const int wave = tid >> 6;
    const int wm   = wave >> 1;
    const int wn   = wave & 1;
    const int l15  = lane & 15;
    const int quad = lane >> 4;

    const int pix_base = blockIdx.x * BN;

    const int bpx = tid >> 2;
    const int bg0 = (tid & 3) * 2;
    const int p   = pix_base + bpx;
    const int n_img = p / HW;
    const int hw    = p - n_img * HW;
    const int h     = hw / W_IN;
    const int w_    = hw - h * W_IN;

    const int ao = tid >> 3;
    const int ag = tid & 7;

    f32x4 acc[4][4];
    #pragma unroll
    for (int t = 0; t < 4; ++t)
        #pragma unroll
        for (int u = 0; u < 4; ++u)
            acc[t][u] = f32x4{0.f, 0.f, 0.f, 0.f};

    for (int pos = 0; pos < 9; ++pos) {
        const int dh = pos / 3 - 1;
        const int dw = pos - (pos / 3) * 3 - 1;
        const int ih = h + dh;
        const int iw = w_ + dw;
        const bool valid = ((unsigned)ih < (unsigned)H_IN) && ((unsigned)iw < (unsigned)W_IN);
        const ushort_t* bsrc = xb + (long)(p + dh * W_IN + dw) * 128;

        #pragma unroll
        for (int half = 0; half < 2; ++half) {
            const int c0 = half * 64;

            {
                const ushort_t* wsrc = wbf + pos * 32768 + c0;
                #pragma unroll
                for (int sj = 0; sj < 4; ++sj) {
                    const int o = ao + sj * 64;
                    ushort8 v = *(const ushort8*)(wsrc + (o << 7) + ag * 8);
                    *(ushort8*)(&As[o * LDSW + ((ag ^ (o & 7)) * 8)]) = v;
                }
            }
            {
                #pragma unroll
                for (int q = 0; q < 2; ++q) {
                    const int g = bg0 + q;
                    ushort8 v;
                    if (valid) v = *(const ushort8*)(bsrc + c0 + g * 8);
                    else       v = ushort8{0,0,0,0,0,0,0,0};
                    *(ushort8*)(&Bs[bpx * LDSW + ((g ^ (bpx & 7)) * 8)]) = v;
                }
            }
            __syncthreads();

            #pragma unroll
            for (int ks = 0; ks < 2; ++ks) {
                bf16x8 af[4], bfv[4];
                const int k16 = ks * 4 + quad;
                #pragma unroll
                for (int t = 0; t < 4; ++t) {
                    const int row = wm * 64 + t * 16 + l15;
                    af[t] = *(const bf16x8*)(&As[row * LDSW + ((k16 ^ (row & 7)) * 8)]);
                }
                #pragma unroll
                for (int u = 0; u < 4; ++u) {
                    const int col = wn * 64 + u * 16 + l15;
                    bfv[u] = *(const bf16x8*)(&Bs[col * LDSW + ((k16 ^ (col & 7)) * 8)]);
                }
                #pragma unroll
                for (int t = 0; t < 4; ++t)
                    #pragma unroll
                    for (int u = 0; u < 4; ++u)
                        acc[t][u] = __builtin_amdgcn_mfma_f32_16x16x32_bf16(af[t], bfv[u], acc[t][u], 0, 0, 0);
            }
            __syncthreads();
        }
    }

    #pragma unroll
    for (int u = 0; u < 4; ++u) {
        const int col = wn * 64 + u * 16 + l15;
        const int pp  = pix_base + col;
        const int nn  = pp / HW;
        const int hw2 = pp - nn * HW;
        const long obase = (long)nn * OHW + hw2;
        #pragma unroll
        for (int t = 0; t < 4; ++t) {
            const int o_base = wm * 64 + t * 16 + quad * 4;
            #pragma unroll
            for (int r = 0; r < 4; ++r) {
                const int o = o_base + r;
                out[obase + (long)o * HW] = acc[t][u][r] + bias[o];
            }
        }
    }
}

__global__ __launch_bounds__(512, 4)
void conv_kernel(const float* __restrict__ x, const ushort_t* __restrict__ wbf,
                 const float* __restrict__ bias, float* __restrict__ out) {
    __shared__ ushort_t As[BM * LDK];
    __shared__ ushort_t Bs[BN * LDK];

    const int tid  = threadIdx.x;
    const int lane = tid & 63;
    const int wave = tid >> 6;
    const int wm   = wave >> 1;
    const int wn   = wave & 1;
    const int l15  = lane & 15;
    const int quad = lane >> 4;

    const int pix_base = blockIdx.x * BN;
    const int px  = tid & 127;
    const int cg0 = tid >> 7;
    const int p   = pix_base + px;
    const int n_img = p / HW;
    const int hw    = p - n_img * HW;
    const int h     = hw / W_IN;
    const int w_    = hw - h * W_IN;
    const float* ximg = x + (long)n_img * CHW;

    f32x4 acc[4][4];
    #pragma unroll
    for (int t = 0; t < 4; ++t)
        #pragma unroll
        for (int u = 0; u < 4; ++u)
            acc[t][u] = f32x4{0.f, 0.f, 0.f, 0.f};

    for (int pos = 0; pos < 9; ++pos) {
        const int dh = pos / 3 - 1;
        const int dw = pos - (pos / 3) * 3 - 1;
        const int ih = h + dh;
        const int iw = w_ + dw;
        const bool valid = ((unsigned)ih < (unsigned)H_IN) && ((unsigned)iw < (unsigned)W_IN);
        const float* xsrc = ximg + ih * W_IN + iw;

        for (int half = 0; half < 2; ++half) {
            const int c0 = half * 64;
            {
                const ushort_t* wsrc = wbf + ((pos * 256) << 7) + c0;
                #pragma unroll
                for (int sj = 0; sj < 4; ++sj) {
                    const int o  = (tid >> 3) + sj * 64;
                    const int cg = tid & 7;
                    ushort8 v = *(const ushort8*)(wsrc + (o << 7) + cg * 8);
                    *(ushort8*)(&As[o * LDK + cg * 8]) = v;
                }
            }
            {
                #pragma unroll
                for (int sj = 0; sj < 2; ++sj) {
                    const int cg = cg0 + sj * 4;
                    const float* src = xsrc + (long)(c0 + cg * 8) * HW;
                    ushort8 v;
                    #pragma unroll
                    for (int j = 0; j < 8; ++j) {
                        float f = valid ? src[j * HW] : 0.0f;
                        v[j] = f2bf(f);
                    }
                    *(ushort8*)(&Bs[px * LDK + cg * 8]) = v;
                }
            }
            __syncthreads();

            #pragma unroll
            for (int ks = 0; ks < 2; ++ks) {
                bf16x8 af[4], bfv[4];
                #pragma unroll
                for (int t = 0; t < 4; ++t) {
                    const int row = wm * 64 + t * 16 + l15;
                    af[t] = *(const bf16x8*)(&As[row * LDK + ks * 32 + quad * 8]);
                }
                #pragma unroll
                for (int u = 0; u < 4; ++u) {
                    const int col = wn * 64 + u * 16 + l15;
                    bfv[u] = *(const bf16x8*)(&Bs[col * LDK + ks * 32 + quad * 8]);
                }
                #pragma unroll
                for (int t = 0; t < 4; ++t)
                    #pragma unroll
                    for (int u = 0; u < 4; ++u)
                        acc[t][u] = __builtin_amdgcn_mfma_f32_16x16x32_bf16(af[t], bfv[u], acc[t][u], 0, 0, 0);
            }
            __syncthreads();
        }
    }

    #pragma unroll
    for (int u = 0; u < 4; ++u) {
        const int col = wn * 64 + u * 16 + l15;
        const int pp  = pix_base + col;
        const int hw2 = pp - (pp / HW) * HW;
        const long obase = (long)(pp / HW) * OHW + hw2;
        #pragma unroll
        for (int t = 0; t < 4; ++t) {
            const int o_base = wm * 64 + t * 16 + quad * 4;
            #pragma unroll
            for (int r = 0; r < 4; ++r) {
                const int o = o_base + r;
                out[obase + (long)o * HW] = acc[t][u][r] + bias[o];
            }
        }
    }
}

extern "C" void kernel_launch(void* const* d_in, const int* in_sizes, int n_in,
                              void* d_out, int out_size, void* d_ws, size_t ws_size,
                              hipStream_t stream) {
    const float* x    = (const float*)d_in[0];
    const float* w    = (const float*)d_in[1];
    const float* bias = (const float*)d_in[2];
    float* out        = (float*)d_out;

    // new path: wbf (589,824 B, swizzled stage-linear) + xbp (padded 58x58 NHWC, 27,557,888 B)
    const size_t NEED_NEW = 589824u + 27557888u;    // 28,147,712
    // old path: wbf (589,824 B, plain) + xb (25,690,112 B)
    const size_t NEED_OLD = 589824u + 25690112u;    // 26,279,936

    if (ws_size >= NEED_NEW) {
        ushort_t* wbf2 = (ushort_t*)d_ws;
        ushort_t* xbp  = (ushort_t*)((char*)d_ws + 589824);
        hipLaunchKernelGGL(wt2_kernel, dim3(1152), dim3(256), 0, stream, w, wbf2);
        hipLaunchKernelGGL(xt2_kernel, dim3(1856), dim3(256), 0, stream, x, xbp);
        hipLaunchKernelGGL(conv3_kernel, dim3(448), dim3(512), 0, stream,
                           xbp, wbf2, bias, out);
    } else if (ws_size >= NEED_OLD) {
        ushort_t* wbf = (ushort_t*)d_ws;
        ushort_t* xb  = (ushort_t*)((char*)d_ws + 589824);
        hipLaunchKernelGGL(wt_kernel, dim3(1152), dim3(256), 0, stream, w, wbf);
        hipLaunchKernelGGL(xt_kernel, dim3(1568), dim3(256), 0, stream, x, xb);
        hipLaunchKernelGGL(conv2_kernel, dim3(100352 / BN), dim3(512), 0, stream,
                           xb, wbf, bias, out);
    } else {
        ushort_t* wbf = (ushort_t*)d_ws;
        hipLaunchKernelGGL(wt_kernel, dim3(1152), dim3(256), 0, stream, w, wbf);
        hipLaunchKernelGGL(conv_kernel, dim3(100352 / BN), dim3(512), 0, stream,
                           x, wbf, bias, out);
    }
}

// Round 3
// 226.857 us; speedup vs baseline: 1.0477x; 1.0477x over previous
//
#include <hip/hip_runtime.h>

#define C_IN   128
#define H_IN   56
#define W_IN   56
#define HW     3136      // 56*56
#define CHW    401408    // 128*3136
#define O_OUT  256
#define OHW    802816    // 256*3136

#define LDK 72           // fallback padded layout

typedef __bf16 bf16x8 __attribute__((ext_vector_type(8)));
typedef float  f32x4  __attribute__((ext_vector_type(4)));
typedef unsigned short ushort_t;
typedef ushort_t ushort8 __attribute__((ext_vector_type(8)));

__device__ __forceinline__ ushort_t f2bf(float f) {
    union { float f; unsigned u; } v; v.f = f;
    unsigned r = (v.u + 0x7fffu + ((v.u >> 16) & 1u)) >> 16;
    return (ushort_t)r;
}

// ============================ NEW FAST PATH ============================
// Weights: w[o][c][kh][kw] fp32 -> wbf[s][o][c&63] bf16, s = (kh*3+kw)*2 + (c>>6).
// Plain (unswizzled) layout: conv6 loads A-fragments straight from global/L2.
__global__ void wt3_kernel(const float* __restrict__ w, ushort_t* __restrict__ wbf) {
    int idx = blockIdx.x * 256 + threadIdx.x;        // 9*256*128 = 294912
    if (idx >= 9 * 256 * 128) return;
    int pos = idx >> 15;
    int rem = idx & 32767;
    int o   = rem >> 7;
    int c   = rem & 127;
    int s   = pos * 2 + (c >> 6);
    wbf[((s * 256 + o) << 6) + (c & 63)] = f2bf(w[o * 1152 + c * 9 + pos]);
}

// Fused conv: integrated fp32->bf16 staging + barrier-free implicit GEMM.
//  - block = 2 output rows x 56 w x 256 o; 256 threads (4 waves, one o-slice each)
//  - patch: 4 padded rows x 58 x 128ch bf16, XOR-swizzled, 59392 B -> 2 blocks/CU
//  - weights: per-lane global_load_dwordx4 from L2 every stage; NO LDS, NO barriers
//  - main loop has zero __syncthreads / zero vmcnt(0) drains
__global__ __launch_bounds__(256, 2)
void conv6_kernel(const float* __restrict__ x, const ushort_t* __restrict__ wbf,
                  const float* __restrict__ bias, float* __restrict__ out) {
    __shared__ ushort_t patch[232 * 128];   // 59,392 B (4 rows x 58 cols x 128 ch)

    const int tid  = threadIdx.x;
    const int lane = tid & 63;
    const int wave = tid >> 6;      // 0..3 -> o-slice
    const int l15  = lane & 15;
    const int quad = lane >> 4;
    const int om   = wave * 64;

    // block -> (n, h0), XCD-aware bijective swizzle (896 = 8 * 112)
    int b = blockIdx.x;
    b = (b & 7) * 112 + (b >> 3);
    const int n  = b / 28;
    const int h0 = (b - n * 28) * 2;

    // ---- integrated staging: x fp32 NCHW -> patch bf16 [pp][slot^] ----
    if (tid < 232) {
        const int pr = tid / 58;              // padded row 0..3
        const int wp = tid - pr * 58;         // padded col 0..57
        const int ih = h0 - 1 + pr;
        const int iw = wp - 1;
        const bool ok = ((unsigned)ih < 56u) && ((unsigned)iw < 56u);
        const float* xs = x + (size_t)n * CHW + ih * W_IN + iw;
        ushort_t* dst = patch + tid * 128;
        const int wkey = wp & 7;
        #pragma unroll
        for (int cg = 0; cg < 16; ++cg) {
            ushort8 v;
            #pragma unroll
            for (int j = 0; j < 8; ++j) {
                float f = 0.0f;
                if (ok) f = xs[(size_t)(cg * 8 + j) * HW];
                v[j] = f2bf(f);
            }
            *(ushort8*)(dst + (((cg ^ wkey)) << 3)) = v;
        }
    }
    __syncthreads();   // the ONLY barrier

    // per-lane B geometry (7 pixel fragments of 16)
    int ppix[7], wk[7], obo[7];
    #pragma unroll
    for (int u = 0; u < 7; ++u) {
        int pix = u * 16 + l15;               // 0..111
        int pr  = (pix >= 56) ? 1 : 0;
        int ww  = pix - pr * 56;
        ppix[u] = (pr * 58 + ww) * 128;       // ushort idx at (kh=0,kw=0)
        wk[u]   = ww;
        obo[u]  = (h0 + pr) * W_IN + ww;
    }

    // per-lane A offsets within a weight stage: o*64 + quad*8 (ushorts)
    int aoff[4];
    #pragma unroll
    for (int t = 0; t < 4; ++t)
        aoff[t] = ((om + t * 16 + l15) << 6) + (quad << 3);

    f32x4 acc[4][7];
    #pragma unroll
    for (int t = 0; t < 4; ++t)
        #pragma unroll
        for (int u = 0; u < 7; ++u)
            acc[t][u] = f32x4{0.f, 0.f, 0.f, 0.f};

    for (int kh = 0; kh < 3; ++kh) {
        #pragma unroll
        for (int kw = 0; kw < 3; ++kw) {
            const int poff = (kh * 58 + kw) * 128;
            #pragma unroll
            for (int half = 0; half < 2; ++half) {
                const int s = (kh * 3 + kw) * 2 + half;
                const ushort_t* wsp = wbf + (size_t)s * 16384;
                #pragma unroll
                for (int ks = 0; ks < 2; ++ks) {
                    bf16x8 af[4], bfv[7];
                    #pragma unroll
                    for (int t = 0; t < 4; ++t)
                        af[t] = *(const bf16x8*)(wsp + aoff[t] + ks * 32);
                    const int k16 = half * 8 + ks * 4 + quad;
                    #pragma unroll
                    for (int u = 0; u < 7; ++u) {
                        const int slot = k16 ^ ((wk[u] + kw) & 7);
                        bfv[u] = *(const bf16x8*)(patch + ppix[u] + poff + (slot << 3));
                    }
                    #pragma unroll
                    for (int t = 0; t < 4; ++t)
                        #pragma unroll
                        for (int u = 0; u < 7; ++u)
                            acc[t][u] = __builtin_amdgcn_mfma_f32_16x16x32_bf16(
                                            af[t], bfv[u], acc[t][u], 0, 0, 0);
                }
            }
        }
    }

    // ---- epilogue ----
    f32x4 bv[4];
    #pragma unroll
    for (int t = 0; t < 4; ++t)
        bv[t] = *(const f32x4*)(bias + om + t * 16 + quad * 4);
    float* outn = out + (size_t)n * OHW;
    #pragma unroll
    for (int u = 0; u < 7; ++u) {
        float* op = outn + obo[u];
        #pragma unroll
        for (int t = 0; t < 4; ++t) {
            const int o0 = om + t * 16 + quad * 4;
            #pragma unroll
            for (int r = 0; r < 4; ++r)
                op[(size_t)(o0 + r) * HW] = acc[t][u][r] + bv[t][r];
        }
    }
}

// ============================ FALLBACK (round-1, known-correct) ============================

__global__ void wt_kernel(const float* __restrict__ w, ushort_t* __restrict__ wbf) {
    int idx = blockIdx.x * 256 + threadIdx.x;        // 9*256*128 = 294912
    if (idx >= 9 * 256 * 128) return;
    int pos = idx >> 15;
    int rem = idx & 32767;
    int o   = rem >> 7;
    int c   = rem & 127;
    wbf[idx] = f2bf(w[o * 1152 + c * 9 + pos]);
}

__global__ __launch_bounds__(512, 4)
void conv_kernel(const float* __restrict__ x, const ushort_t* __restrict__ wbf,
                 const float* __restrict__ bias, float* __restrict__ out) {
    __shared__ ushort_t As[256 * LDK];
    __shared__ ushort_t Bs[128 * LDK];

    const int tid  = threadIdx.x;
    const int lane = tid & 63;
    const int wave = tid >> 6;
    const int wm   = wave >> 1;
    const int wn   = wave & 1;
    const int l15  = lane & 15;
    const int quad = lane >> 4;

    const int pix_base = blockIdx.x * 128;
    const int px  = tid & 127;
    const int cg0 = tid >> 7;
    const int p   = pix_base + px;
    const int n_img = p / HW;
    const int hw    = p - n_img * HW;
    const int h     = hw / W_IN;
    const int w_    = hw - h * W_IN;
    const float* ximg = x + (long)n_img * CHW;

    f32x4 acc[4][4];
    #pragma unroll
    for (int t = 0; t < 4; ++t)
        #pragma unroll
        for (int u = 0; u < 4; ++u)
            acc[t][u] = f32x4{0.f, 0.f, 0.f, 0.f};

    for (int pos = 0; pos < 9; ++pos) {
        const int dh = pos / 3 - 1;
        const int dw = pos - (pos / 3) * 3 - 1;
        const int ih = h + dh;
        const int iw = w_ + dw;
        const bool valid = ((unsigned)ih < (unsigned)H_IN) && ((unsigned)iw < (unsigned)W_IN);
        const float* xsrc = ximg + ih * W_IN + iw;

        for (int half = 0; half < 2; ++half) {
            const int c0 = half * 64;
            {
                const ushort_t* wsrc = wbf + ((pos * 256) << 7) + c0;
                #pragma unroll
                for (int sj = 0; sj < 4; ++sj) {
                    const int o  = (tid >> 3) + sj * 64;
                    const int cg = tid & 7;
                    ushort8 v = *(const ushort8*)(wsrc + (o << 7) + cg * 8);
                    *(ushort8*)(&As[o * LDK + cg * 8]) = v;
                }
            }
            {
                #pragma unroll
                for (int sj = 0; sj < 2; ++sj) {
                    const int cg = cg0 + sj * 4;
                    const float* src = xsrc + (long)(c0 + cg * 8) * HW;
                    ushort8 v;
                    #pragma unroll
                    for (int j = 0; j < 8; ++j) {
                        float f = valid ? src[j * HW] : 0.0f;
                        v[j] = f2bf(f);
                    }
                    *(ushort8*)(&Bs[px * LDK + cg * 8]) = v;
                }
            }
            __syncthreads();

            #pragma unroll
            for (int ks = 0; ks < 2; ++ks) {
                bf16x8 af[4], bfv[4];
                #pragma unroll
                for (int t = 0; t < 4; ++t) {
                    const int row = wm * 64 + t * 16 + l15;
                    af[t] = *(const bf16x8*)(&As[row * LDK + ks * 32 + quad * 8]);
                }
                #pragma unroll
                for (int u = 0; u < 4; ++u) {
                    const int col = wn * 64 + u * 16 + l15;
                    bfv[u] = *(const bf16x8*)(&Bs[col * LDK + ks * 32 + quad * 8]);
                }
                #pragma unroll
                for (int t = 0; t < 4; ++t)
                    #pragma unroll
                    for (int u = 0; u < 4; ++u)
                        acc[t][u] = __builtin_amdgcn_mfma_f32_16x16x32_bf16(af[t], bfv[u], acc[t][u], 0, 0, 0);
            }
            __syncthreads();
        }
    }

    #pragma unroll
    for (int u = 0; u < 4; ++u) {
        const int col = wn * 64 + u * 16 + l15;
        const int pp  = pix_base + col;
        const int hw2 = pp - (pp / HW) * HW;
        const long obase = (long)(pp / HW) * OHW + hw2;
        #pragma unroll
        for (int t = 0; t < 4; ++t) {
            const int o_base = wm * 64 + t * 16 + quad * 4;
            #pragma unroll
            for (int r = 0; r < 4; ++r) {
                const int o = o_base + r;
                out[obase + (long)o * HW] = acc[t][u][r] + bias[o];
            }
        }
    }
}

extern "C" void kernel_launch(void* const* d_in, const int* in_sizes, int n_in,
                              void* d_out, int out_size, void* d_ws, size_t ws_size,
                              hipStream_t stream) {
    const float* x    = (const float*)d_in[0];
    const float* w    = (const float*)d_in[1];
    const float* bias = (const float*)d_in[2];
    float* out        = (float*)d_out;

    ushort_t* wbf = (ushort_t*)d_ws;                 // 589,824 B

    if (ws_size >= 589824u) {
        hipLaunchKernelGGL(wt3_kernel, dim3(1152), dim3(256), 0, stream, w, wbf);
        hipLaunchKernelGGL(conv6_kernel, dim3(896), dim3(256), 0, stream,
                           x, wbf, bias, out);
    } else {
        // (unreachable in practice; requires same wbf workspace)
        hipLaunchKernelGGL(wt_kernel, dim3(1152), dim3(256), 0, stream, w, wbf);
        hipLaunchKernelGGL(conv_kernel, dim3(100352 / 128), dim3(512), 0, stream,
                           x, wbf, bias, out);
    }
}